// Round 5
// baseline (763.381 us; speedup 1.0000x reference)
//
#include <hip/hip_runtime.h>
#include <hip/hip_bf16.h>

#define NTOK 2048
#define DIM 512
#define HID 2048
#define NEXP 64
#define NSLICE 16
#define HSLICE 128   // HID / NSLICE
#define TTM 128      // token capacity per weight pass
#define LN_EPS 1e-5f

// LDS layout (bytes), 52 KB/block -> 3 blocks/CU (launch_bounds(256,3)).
//   [0, 10240)       Ws0 : 128 cols x 80 B (32 k bf16 + pad, kg-xor swizzled)
//   [10240, 20480)   Ws1 : double buffer (round-4 lesson: the syncthreads
//                          vmcnt(0) drain made each 16KB step ~13K cycles;
//                          lgkm-only barriers + dbuf keep loads in flight)
//   [20480, 53248)   Hs  : 128 tok x 128 h bf16, row 256 B, xor-swizzled
#define WS0_OFF 0
#define WS1_OFF 10240
#define HS_OFF  20480
#define SMEM_BYTES 53248

typedef __bf16 bf16x8 __attribute__((ext_vector_type(8)));
typedef __bf16 bf16x4 __attribute__((ext_vector_type(4)));
typedef float f32x4 __attribute__((ext_vector_type(4)));

// Raw barrier with lgkmcnt(0) ONLY: LDS writes visible to the group, but
// global loads AND the epilogue's fire-and-forget atomics stay in flight.
#define LGKM_BARRIER() do { \
    asm volatile("s_waitcnt lgkmcnt(0)" ::: "memory"); \
    __builtin_amdgcn_s_barrier(); \
} while (0)

// ---------------- init: zero expert counts (accb zeroing fused into gate) ---
__global__ void init_kernel(int* __restrict__ counts) {
    counts[threadIdx.x] = 0;
}

// ---------------- gating: softmax + top2 + bucket (+ zero accb row) --------
__global__ void gate_kernel(const float* __restrict__ x,
                            const float* __restrict__ Wg,
                            const float* __restrict__ bg,
                            int* __restrict__ counts,
                            int* __restrict__ btok,
                            float* __restrict__ bw,
                            float4* __restrict__ accb4) {
    const int t = blockIdx.x;
    const int lane = threadIdx.x;  // 64 threads = 1 wave
    // zero this token's accumulator row (was init_kernel's job)
    const float4 z = make_float4(0.f, 0.f, 0.f, 0.f);
    accb4[(size_t)t * (DIM / 4) + lane] = z;
    accb4[(size_t)t * (DIM / 4) + lane + 64] = z;

    __shared__ float xs[DIM];
    const float4* xrow = (const float4*)(x + (size_t)t * DIM);
    ((float4*)xs)[lane] = xrow[lane];
    ((float4*)xs)[lane + 64] = xrow[lane + 64];
    __syncthreads();

    float acc = bg[lane];
    #pragma unroll 8
    for (int d = 0; d < DIM; d++) acc += xs[d] * Wg[d * NEXP + lane];

    float m = acc;
    #pragma unroll
    for (int off = 32; off; off >>= 1) m = fmaxf(m, __shfl_xor(m, off));
    float p = __expf(acc - m);
    float ssum = p;
    #pragma unroll
    for (int off = 32; off; off >>= 1) ssum += __shfl_xor(ssum, off);
    float prob = p / ssum;

    float v1 = prob; int i1 = lane;
    #pragma unroll
    for (int off = 32; off; off >>= 1) {
        float ov = __shfl_xor(v1, off);
        int   oi = __shfl_xor(i1, off);
        if (ov > v1 || (ov == v1 && oi < i1)) { v1 = ov; i1 = oi; }
    }
    float v2 = (lane == i1) ? -1e30f : prob; int i2 = lane;
    #pragma unroll
    for (int off = 32; off; off >>= 1) {
        float ov = __shfl_xor(v2, off);
        int   oi = __shfl_xor(i2, off);
        if (ov > v2 || (ov == v2 && oi < i2)) { v2 = ov; i2 = oi; }
    }

    if (lane == 0) {
        int s0 = atomicAdd(&counts[i1], 1);
        btok[i1 * NTOK + s0] = t;  bw[i1 * NTOK + s0] = v1;
        int s1 = atomicAdd(&counts[i2], 1);
        btok[i2 * NTOK + s1] = t;  bw[i2 * NTOK + s1] = v2;
    }
}

// Ws element offset (bf16 units) for (col 0..127, kgroup 0..3 of 8 k-values).
__device__ __forceinline__ int ws_off(int col, int kg) {
    return col * 40 + ((kg ^ ((col >> 3) & 3)) << 3);
}

// Load a 4-row x 4-col fp32 patch of a weight tile into registers.
__device__ __forceinline__ void wload(const float* __restrict__ wp, size_t rs,
                                      float4 wv[4]) {
    #pragma unroll
    for (int u = 0; u < 4; u++) wv[u] = *(const float4*)(wp + (size_t)u * rs);
}

// Convert + write the 4x4 register patch into a Ws buffer.
__device__ __forceinline__ void wstore(__bf16* __restrict__ wsb, int c0, int r0,
                                       const float4 wv[4]) {
    #pragma unroll
    for (int j = 0; j < 4; j++) {
        const float* f0 = (const float*)&wv[0];
        const float* f1 = (const float*)&wv[1];
        const float* f2 = (const float*)&wv[2];
        const float* f3 = (const float*)&wv[3];
        bf16x4 pk;
        pk[0] = (__bf16)f0[j]; pk[1] = (__bf16)f1[j];
        pk[2] = (__bf16)f2[j]; pk[3] = (__bf16)f3[j];
        *(bf16x4*)(wsb + ws_off(c0 + j, r0 >> 3) + (r0 & 7)) = pk;
    }
}

__device__ __forceinline__ bf16x8 acvt(float4 a0, float4 a1) {
    bf16x8 v;
    const float* f0 = (const float*)&a0;
    const float* f1 = (const float*)&a1;
    #pragma unroll
    for (int j = 0; j < 4; j++) { v[j] = (__bf16)f0[j]; v[4 + j] = (__bf16)f1[j]; }
    return v;
}

// ---------------- grouped FFN: per (expert, H-slice) block ----------------
// Double-buffered Ws + depth-1 register prefetch, one lgkm-only barrier per
// K-step: weight loads for tile k+1 are in flight across the whole of step k.
__global__ __launch_bounds__(256, 3) void ffn_kernel(
    const float* __restrict__ x,
    const float* __restrict__ W1, const float* __restrict__ b1,
    const float* __restrict__ W2, const float* __restrict__ b2,
    const int* __restrict__ counts,
    const int* __restrict__ btok, const float* __restrict__ bw,
    float* __restrict__ accb)
{
    __shared__ char smem[SMEM_BYTES];
    __bf16* ws0 = (__bf16*)(smem + WS0_OFF);
    __bf16* ws1 = (__bf16*)(smem + WS1_OFF);

    const int e = blockIdx.x >> 4;
    const int s = blockIdx.x & 15;
    const int n = counts[e];
    if (n <= 0) return;

    const int tid  = threadIdx.x;
    const int lane = tid & 63;
    const int wid  = tid >> 6;
    const int lq   = lane >> 4;                   // quad 0..3
    const int lm   = lane & 15;
    const int c0   = (tid & 31) * 4;              // staging: 4 cols
    const int r0   = (tid >> 5) * 4;              // staging: 4 k-rows

    const float* W1s = W1 + (size_t)e * DIM * HID + s * HSLICE;           // row stride HID
    const float* W2s = W2 + ((size_t)e * HID + (size_t)s * HSLICE) * DIM; // row stride DIM
    const int*   btoke = btok + e * NTOK;
    const float* bwe   = bw   + e * NTOK;

    for (int t0 = 0; t0 < n; t0 += TTM) {         // almost always 1 iteration
        const int tiln = min(TTM, n - t0);
        const bool two = (tiln > 64);             // block-uniform

        const int tra0 = wid * 16 + lm;
        const int tok0 = btoke[t0 + (tra0 < tiln ? tra0 : 0)];
        const int tra1 = 64 + tra0;
        const int tok1 = two ? btoke[t0 + (tra1 < tiln ? tra1 : 0)] : tok0;
        const float* xrow0 = x + (size_t)tok0 * DIM;
        const float* xrow1 = x + (size_t)tok1 * DIM;

        // ---- Phase A: h[tiln x 128] = relu(X @ W1slice + b1) ----
        f32x4 acc0[8], acc1[8];
        #pragma unroll
        for (int i = 0; i < 8; i++) { acc0[i] = (f32x4)0.0f; acc1[i] = (f32x4)0.0f; }

        float4 wv[4];
        {   // prologue: stage tile 0 into ws0, put tile 1 in flight
            float4 w0[4];
            wload(W1s + (size_t)r0 * HID + c0, HID, w0);
            wstore(ws0, c0, r0, w0);               // waits tile-0 loads only
            wload(W1s + (size_t)(32 + r0) * HID + c0, HID, wv);
            LGKM_BARRIER();
        }
        int cur = 0;

        for (int ks = 0; ks < 16; ks++) {
            // A fragments for this step (x is L2/L3-resident)
            float4 a00 = *(const float4*)(xrow0 + ks * 32 + lq * 8);
            float4 a01 = *(const float4*)(xrow0 + ks * 32 + lq * 8 + 4);
            float4 a10, a11;
            if (two) {
                a10 = *(const float4*)(xrow1 + ks * 32 + lq * 8);
                a11 = *(const float4*)(xrow1 + ks * 32 + lq * 8 + 4);
            }
            bf16x8 af0 = acvt(a00, a01), af1;
            if (two) af1 = acvt(a10, a11);

            const __bf16* wr = cur ? ws1 : ws0;
            #pragma unroll
            for (int nt = 0; nt < 8; nt++) {
                bf16x8 bfv = *(const bf16x8*)(wr + ws_off(nt * 16 + lm, lq));
                acc0[nt] = __builtin_amdgcn_mfma_f32_16x16x32_bf16(af0, bfv, acc0[nt], 0, 0, 0);
                if (two)
                    acc1[nt] = __builtin_amdgcn_mfma_f32_16x16x32_bf16(af1, bfv, acc1[nt], 0, 0, 0);
            }
            if (ks < 15) {
                __bf16* ww = cur ? ws0 : ws1;
                wstore(ww, c0, r0, wv);            // tile ks+1 -> other buffer
                if (ks < 14)
                    wload(W1s + (size_t)((ks + 2) * 32 + r0) * HID + c0, HID, wv);
                LGKM_BARRIER();                    // loads stay in flight
                cur ^= 1;
            }
        }

        // relu + b1 -> Hs rows of THIS wave only (no cross-wave dependency)
        #pragma unroll
        for (int nt = 0; nt < 8; nt++) {
            int hloc = nt * 16 + lm;
            float b1v = b1[e * HID + s * HSLICE + hloc];
            #pragma unroll
            for (int r = 0; r < 4; r++) {
                int tr = wid * 16 + lq * 4 + r;
                float v = fmaxf(acc0[nt][r] + b1v, 0.f);
                *(__bf16*)(smem + HS_OFF + tr * 256 +
                           (((hloc >> 3) ^ (tr & 7)) * 16) + (hloc & 7) * 2) = (__bf16)v;
                if (two) {
                    int tr1 = 64 + tr;
                    float v1 = fmaxf(acc1[nt][r] + b1v, 0.f);
                    *(__bf16*)(smem + HS_OFF + tr1 * 256 +
                               (((hloc >> 3) ^ (tr1 & 7)) * 16) + (hloc & 7) * 2) = (__bf16)v1;
                }
            }
        }
        // no barrier needed: each wave reads back only its own Hs rows.

        // ---- Phase B: Y[tiln x 512] = Hs @ W2slice (16 flattened steps) ----
        // After phase A, ws1 was read last (step 15); ws0 is free to write.
        {
            float4 w0[4];
            wload(W2s + (size_t)r0 * DIM + c0, DIM, w0);
            wstore(ws0, c0, r0, w0);
            wload(W2s + (size_t)(32 + r0) * DIM + c0, DIM, wv);
            LGKM_BARRIER();
        }
        cur = 0;
        f32x4 yacc0[8], yacc1[8];

        for (int u = 0; u < 16; u++) {
            const int kk = u & 3, dq = u >> 2;
            if (kk == 0) {
                #pragma unroll
                for (int i = 0; i < 8; i++) { yacc0[i] = (f32x4)0.0f; yacc1[i] = (f32x4)0.0f; }
            }

            const int trb0 = wid * 16 + lm;
            bf16x8 af0 = *(const bf16x8*)(smem + HS_OFF + trb0 * 256 +
                                          (((kk * 4 + lq) ^ (trb0 & 7)) * 16));
            bf16x8 af1;
            if (two) {
                const int trb1 = 64 + trb0;
                af1 = *(const bf16x8*)(smem + HS_OFF + trb1 * 256 +
                                       (((kk * 4 + lq) ^ (trb1 & 7)) * 16));
            }

            const __bf16* wr = cur ? ws1 : ws0;
            #pragma unroll
            for (int nt = 0; nt < 8; nt++) {
                bf16x8 bfv = *(const bf16x8*)(wr + ws_off(nt * 16 + lm, lq));
                yacc0[nt] = __builtin_amdgcn_mfma_f32_16x16x32_bf16(af0, bfv, yacc0[nt], 0, 0, 0);
                if (two)
                    yacc1[nt] = __builtin_amdgcn_mfma_f32_16x16x32_bf16(af1, bfv, yacc1[nt], 0, 0, 0);
            }
            if (u < 15) {
                __bf16* ww = cur ? ws0 : ws1;
                wstore(ww, c0, r0, wv);
                if (u < 14) {
                    const int un = u + 2;
                    wload(W2s + (size_t)((un & 3) * 32 + r0) * DIM + (un >> 2) * 128 + c0,
                          DIM, wv);
                }
                LGKM_BARRIER();
                cur ^= 1;
            }
            if (kk == 3) {
                // epilogue for d-quarter dq: weighted atomic combine.
                // Runs after the barrier: atomics overlap the next tile's
                // loads and are never drained by a barrier (lgkm-only).
                float b2s[8];
                #pragma unroll
                for (int nt = 0; nt < 8; nt++) {
                    int d = dq * 128 + nt * 16 + lm;
                    b2s[nt] = (s == 0) ? b2[e * DIM + d] : 0.f;
                }
                #pragma unroll
                for (int r = 0; r < 4; r++) {
                    int tr = wid * 16 + lq * 4 + r;
                    if (tr < tiln) {
                        int tok2 = btoke[t0 + tr];
                        float w = bwe[t0 + tr];
                        float* dst = accb + (size_t)tok2 * DIM;
                        #pragma unroll
                        for (int nt = 0; nt < 8; nt++) {
                            int d = dq * 128 + nt * 16 + lm;
                            atomicAdd(dst + d, w * (yacc0[nt][r] + b2s[nt]));
                        }
                    }
                    if (two) {
                        int tr1 = 64 + tr;
                        if (tr1 < tiln) {
                            int tok2 = btoke[t0 + tr1];
                            float w = bwe[t0 + tr1];
                            float* dst = accb + (size_t)tok2 * DIM;
                            #pragma unroll
                            for (int nt = 0; nt < 8; nt++) {
                                int d = dq * 128 + nt * 16 + lm;
                                atomicAdd(dst + d, w * (yacc1[nt][r] + b2s[nt]));
                            }
                        }
                    }
                }
            }
        }
        // Pass-to-pass (rare): next phase-A prologue writes ws0; its last
        // readers were step u=14, already fenced by that step's barrier.
    }
}

// ---------------- residual + LayerNorm ----------------
__global__ void ln_kernel(const float* __restrict__ x,
                          const float* __restrict__ accb,
                          const float* __restrict__ gamma,
                          const float* __restrict__ beta,
                          float* __restrict__ out) {
    const int t = blockIdx.x;
    const int tid = threadIdx.x;                  // 256
    __shared__ float red[8];
    const size_t base = (size_t)t * DIM;
    float v0 = x[base + tid] + accb[base + tid];
    float v1 = x[base + 256 + tid] + accb[base + 256 + tid];
    float s  = v0 + v1;
    float sq = v0 * v0 + v1 * v1;
    #pragma unroll
    for (int off = 32; off; off >>= 1) { s += __shfl_xor(s, off); sq += __shfl_xor(sq, off); }
    if ((tid & 63) == 0) { red[tid >> 6] = s; red[4 + (tid >> 6)] = sq; }
    __syncthreads();
    float S  = red[0] + red[1] + red[2] + red[3];
    float SQ = red[4] + red[5] + red[6] + red[7];
    float mu  = S * (1.f / DIM);
    float var = SQ * (1.f / DIM) - mu * mu;
    float inv = rsqrtf(var + LN_EPS);
    out[base + tid]       = (v0 - mu) * inv * gamma[tid]       + beta[tid];
    out[base + 256 + tid] = (v1 - mu) * inv * gamma[256 + tid] + beta[256 + tid];
}

extern "C" void kernel_launch(void* const* d_in, const int* in_sizes, int n_in,
                              void* d_out, int out_size, void* d_ws, size_t ws_size,
                              hipStream_t stream) {
    const float* x     = (const float*)d_in[0];
    const float* Wg    = (const float*)d_in[1];
    const float* bg    = (const float*)d_in[2];
    const float* W1    = (const float*)d_in[3];
    const float* b1    = (const float*)d_in[4];
    const float* W2    = (const float*)d_in[5];
    const float* b2    = (const float*)d_in[6];
    const float* gamma = (const float*)d_in[7];
    const float* beta  = (const float*)d_in[8];

    char* ws = (char*)d_ws;
    int*   counts = (int*)ws;                                  // 256 B
    int*   btok   = (int*)(ws + 4096);                          // 512 KB
    float* bwv    = (float*)(ws + 4096 + 524288);               // 512 KB
    float* accb   = (float*)(ws + 4096 + 2 * 524288);           // 4 MB

    init_kernel<<<1, NEXP, 0, stream>>>(counts);
    gate_kernel<<<NTOK, 64, 0, stream>>>(x, Wg, bg, counts, btok, bwv,
                                         (float4*)accb);
    ffn_kernel<<<NEXP * NSLICE, 256, 0, stream>>>(x, W1, b1, W2, b2,
                                                  counts, btok, bwv, accb);
    ln_kernel<<<NTOK, 256, 0, stream>>>(x, accb, gamma, beta, (float*)d_out);
}

// Round 6
// 666.831 us; speedup vs baseline: 1.1448x; 1.1448x over previous
//
#include <hip/hip_runtime.h>
#include <hip/hip_bf16.h>

#define NTOK 2048
#define DIM 512
#define HID 2048
#define NEXP 64
#define NSLICE 16
#define HSLICE 128   // HID / NSLICE
#define TTM 112      // token capacity per weight pass (binomial max ~87 << 112)
#define LN_EPS 1e-5f

// LDS layout (bytes), 38 KB/block -> 4 blocks/CU (launch_bounds(256,4)).
// Grid = 1024 = 256 CU x 4 blocks: fully resident, zero dispatch tail
// (round-4 lesson: 43KB -> 3/CU cost a residency slot + 256-block tail).
//   [0, 10240)       Ws : 128 cols x 80 B (32 k bf16 + 16B pad, kg-xor swizzled)
//   [10240, 38912)   Hs : 112 tok x 128 h bf16, row 256 B, xor-swizzled chunks
#define WS_OFF 0
#define HS_OFF 10240
#define SMEM_BYTES 38912

typedef __bf16 bf16x8 __attribute__((ext_vector_type(8)));
typedef __bf16 bf16x4 __attribute__((ext_vector_type(4)));
typedef float f32x4 __attribute__((ext_vector_type(4)));

// ---------------- init: zero expert counts (accb zeroing fused into gate) ---
__global__ void init_kernel(int* __restrict__ counts) {
    counts[threadIdx.x] = 0;
}

// ---------------- gating: softmax + top2 + bucket (+ zero accb row) --------
__global__ void gate_kernel(const float* __restrict__ x,
                            const float* __restrict__ Wg,
                            const float* __restrict__ bg,
                            int* __restrict__ counts,
                            int* __restrict__ btok,
                            float* __restrict__ bw,
                            float4* __restrict__ accb4) {
    const int t = blockIdx.x;
    const int lane = threadIdx.x;  // 64 threads = 1 wave
    // zero this token's accumulator row (was init_kernel's job)
    const float4 z = make_float4(0.f, 0.f, 0.f, 0.f);
    accb4[(size_t)t * (DIM / 4) + lane] = z;
    accb4[(size_t)t * (DIM / 4) + lane + 64] = z;

    __shared__ float xs[DIM];
    const float4* xrow = (const float4*)(x + (size_t)t * DIM);
    ((float4*)xs)[lane] = xrow[lane];
    ((float4*)xs)[lane + 64] = xrow[lane + 64];
    __syncthreads();

    float acc = bg[lane];
    #pragma unroll 8
    for (int d = 0; d < DIM; d++) acc += xs[d] * Wg[d * NEXP + lane];

    float m = acc;
    #pragma unroll
    for (int off = 32; off; off >>= 1) m = fmaxf(m, __shfl_xor(m, off));
    float p = __expf(acc - m);
    float ssum = p;
    #pragma unroll
    for (int off = 32; off; off >>= 1) ssum += __shfl_xor(ssum, off);
    float prob = p / ssum;

    float v1 = prob; int i1 = lane;
    #pragma unroll
    for (int off = 32; off; off >>= 1) {
        float ov = __shfl_xor(v1, off);
        int   oi = __shfl_xor(i1, off);
        if (ov > v1 || (ov == v1 && oi < i1)) { v1 = ov; i1 = oi; }
    }
    float v2 = (lane == i1) ? -1e30f : prob; int i2 = lane;
    #pragma unroll
    for (int off = 32; off; off >>= 1) {
        float ov = __shfl_xor(v2, off);
        int   oi = __shfl_xor(i2, off);
        if (ov > v2 || (ov == v2 && oi < i2)) { v2 = ov; i2 = oi; }
    }

    if (lane == 0) {
        int s0 = atomicAdd(&counts[i1], 1);
        btok[i1 * NTOK + s0] = t;  bw[i1 * NTOK + s0] = v1;
        int s1 = atomicAdd(&counts[i2], 1);
        btok[i2 * NTOK + s1] = t;  bw[i2 * NTOK + s1] = v2;
    }
}

// Ws element offset (bf16 units) for (col 0..127, kgroup 0..3 of 8 k-values).
__device__ __forceinline__ int ws_off(int col, int kg) {
    return col * 40 + ((kg ^ ((col >> 3) & 3)) << 3);
}

// ---------------- grouped FFN: per (expert, H-slice) block ----------------
// Round-4 structure (burst loads -> __syncthreads -> stage -> MFMA): both
// in-block pipeline attempts (r1, r5) regressed with spill-signature traffic;
// the working lever is block-level TLP, maximized here (4/CU, no tail).
__global__ __launch_bounds__(256, 4) void ffn_kernel(
    const float* __restrict__ x,
    const float* __restrict__ W1, const float* __restrict__ b1,
    const float* __restrict__ W2, const float* __restrict__ b2,
    const int* __restrict__ counts,
    const int* __restrict__ btok, const float* __restrict__ bw,
    float* __restrict__ accb)
{
    __shared__ char smem[SMEM_BYTES];
    __bf16* wsb = (__bf16*)(smem + WS_OFF);

    const int e = blockIdx.x >> 4;
    const int s = blockIdx.x & 15;
    const int n = counts[e];
    if (n <= 0) return;

    const int tid  = threadIdx.x;
    const int lane = tid & 63;
    const int wid  = tid >> 6;
    const int lq   = lane >> 4;                   // quad 0..3
    const int lm   = lane & 15;
    const int c0   = (tid & 31) * 4;              // staging: 4 cols
    const int r0   = (tid >> 5) * 4;              // staging: 4 k-rows

    const float* W1s = W1 + (size_t)e * DIM * HID + s * HSLICE;           // row stride HID
    const float* W2s = W2 + ((size_t)e * HID + (size_t)s * HSLICE) * DIM; // row stride DIM
    const int*   btoke = btok + e * NTOK;
    const float* bwe   = bw   + e * NTOK;

    for (int t0 = 0; t0 < n; t0 += TTM) {         // one iteration in practice
        const int tiln = min(TTM, n - t0);
        const bool two = (tiln > 64);             // block-uniform

        // wave 'wid' owns tokens g*64 + wid*16 + lm for groups g=0,1.
        // Group-1 rows >= TTM (wid==3) are never valid: guarded below.
        const int tra0 = wid * 16 + lm;
        const int tok0 = btoke[t0 + (tra0 < tiln ? tra0 : 0)];
        const int tra1 = 64 + tra0;
        const int tok1 = two ? btoke[t0 + (tra1 < tiln ? tra1 : 0)] : tok0;
        const float* xrow0 = x + (size_t)tok0 * DIM;
        const float* xrow1 = x + (size_t)tok1 * DIM;

        // ---- Phase A: h[tiln x 128] = relu(X @ W1slice + b1) ----
        f32x4 acc0[8], acc1[8];
        #pragma unroll
        for (int i = 0; i < 8; i++) { acc0[i] = (f32x4)0.0f; acc1[i] = (f32x4)0.0f; }

        for (int ks = 0; ks < 16; ks++) {          // K = 512, 32 per step
            // issue staging + A loads to registers BEFORE the barrier
            float4 wv[4];
            const float* wp = W1s + (size_t)(ks * 32 + r0) * HID + c0;
            #pragma unroll
            for (int u = 0; u < 4; u++) wv[u] = *(const float4*)(wp + (size_t)u * HID);
            float4 a00 = *(const float4*)(xrow0 + ks * 32 + lq * 8);
            float4 a01 = *(const float4*)(xrow0 + ks * 32 + lq * 8 + 4);
            float4 a10, a11;
            if (two) {
                a10 = *(const float4*)(xrow1 + ks * 32 + lq * 8);
                a11 = *(const float4*)(xrow1 + ks * 32 + lq * 8 + 4);
            }

            __syncthreads();                        // prev readers of Ws done
            #pragma unroll
            for (int j = 0; j < 4; j++) {
                const float* f0 = (const float*)&wv[0];
                const float* f1 = (const float*)&wv[1];
                const float* f2 = (const float*)&wv[2];
                const float* f3 = (const float*)&wv[3];
                bf16x4 pk;
                pk[0] = (__bf16)f0[j]; pk[1] = (__bf16)f1[j];
                pk[2] = (__bf16)f2[j]; pk[3] = (__bf16)f3[j];
                *(bf16x4*)(wsb + ws_off(c0 + j, r0 >> 3) + (r0 & 7)) = pk;
            }
            bf16x8 af0, af1;
            {
                const float* f0 = (const float*)&a00;
                const float* f1 = (const float*)&a01;
                #pragma unroll
                for (int j = 0; j < 4; j++) { af0[j] = (__bf16)f0[j]; af0[4 + j] = (__bf16)f1[j]; }
            }
            if (two) {
                const float* f0 = (const float*)&a10;
                const float* f1 = (const float*)&a11;
                #pragma unroll
                for (int j = 0; j < 4; j++) { af1[j] = (__bf16)f0[j]; af1[4 + j] = (__bf16)f1[j]; }
            }
            __syncthreads();                        // Ws tile ready

            #pragma unroll
            for (int nt = 0; nt < 8; nt++) {
                bf16x8 bfv = *(const bf16x8*)(wsb + ws_off(nt * 16 + lm, lq));
                acc0[nt] = __builtin_amdgcn_mfma_f32_16x16x32_bf16(af0, bfv, acc0[nt], 0, 0, 0);
                if (two)
                    acc1[nt] = __builtin_amdgcn_mfma_f32_16x16x32_bf16(af1, bfv, acc1[nt], 0, 0, 0);
            }
        }

        // relu + b1 -> Hs rows of THIS wave only (no cross-wave dependency)
        #pragma unroll
        for (int nt = 0; nt < 8; nt++) {
            int hloc = nt * 16 + lm;
            float b1v = b1[e * HID + s * HSLICE + hloc];
            #pragma unroll
            for (int r = 0; r < 4; r++) {
                int tr = wid * 16 + lq * 4 + r;
                float v = fmaxf(acc0[nt][r] + b1v, 0.f);
                *(__bf16*)(smem + HS_OFF + tr * 256 +
                           (((hloc >> 3) ^ (tr & 7)) * 16) + (hloc & 7) * 2) = (__bf16)v;
                if (two) {
                    int tr1 = 64 + tr;
                    if (tr1 < TTM) {                // rows >= TTM never valid
                        float v1 = fmaxf(acc1[nt][r] + b1v, 0.f);
                        *(__bf16*)(smem + HS_OFF + tr1 * 256 +
                                   (((hloc >> 3) ^ (tr1 & 7)) * 16) + (hloc & 7) * 2) = (__bf16)v1;
                    }
                }
            }
        }
        // no barrier needed: each wave reads back only its own Hs rows.

        // ---- Phase B: Y[tiln x 512] = Hs @ W2slice ----
        for (int dq = 0; dq < 4; dq++) {            // D = 512 in 4 quarters of 128
            f32x4 yacc0[8], yacc1[8];
            #pragma unroll
            for (int i = 0; i < 8; i++) { yacc0[i] = (f32x4)0.0f; yacc1[i] = (f32x4)0.0f; }

            for (int ks = 0; ks < 4; ks++) {        // K = 128 h in 4 steps of 32
                float4 wv[4];
                const float* wp = W2s + (size_t)(ks * 32 + r0) * DIM + dq * 128 + c0;
                #pragma unroll
                for (int u = 0; u < 4; u++) wv[u] = *(const float4*)(wp + (size_t)u * DIM);

                const int trb0 = wid * 16 + lm;
                bf16x8 af0 = *(const bf16x8*)(smem + HS_OFF + trb0 * 256 +
                                              (((ks * 4 + lq) ^ (trb0 & 7)) * 16));
                bf16x8 af1;
                if (two) {
                    const int trb1 = min(64 + trb0, TTM - 1);  // clamp OOB rows
                    af1 = *(const bf16x8*)(smem + HS_OFF + trb1 * 256 +
                                           (((ks * 4 + lq) ^ (trb1 & 7)) * 16));
                }

                __syncthreads();                    // prev readers of Ws done
                #pragma unroll
                for (int j = 0; j < 4; j++) {
                    const float* f0 = (const float*)&wv[0];
                    const float* f1 = (const float*)&wv[1];
                    const float* f2 = (const float*)&wv[2];
                    const float* f3 = (const float*)&wv[3];
                    bf16x4 pk;
                    pk[0] = (__bf16)f0[j]; pk[1] = (__bf16)f1[j];
                    pk[2] = (__bf16)f2[j]; pk[3] = (__bf16)f3[j];
                    *(bf16x4*)(wsb + ws_off(c0 + j, r0 >> 3) + (r0 & 7)) = pk;
                }
                __syncthreads();                    // Ws tile ready

                #pragma unroll
                for (int nt = 0; nt < 8; nt++) {
                    bf16x8 bfv = *(const bf16x8*)(wsb + ws_off(nt * 16 + lm, lq));
                    yacc0[nt] = __builtin_amdgcn_mfma_f32_16x16x32_bf16(af0, bfv, yacc0[nt], 0, 0, 0);
                    if (two)
                        yacc1[nt] = __builtin_amdgcn_mfma_f32_16x16x32_bf16(af1, bfv, yacc1[nt], 0, 0, 0);
                }
            }

            // epilogue for this d-quarter: weighted atomic combine
            float b2s[8];
            #pragma unroll
            for (int nt = 0; nt < 8; nt++) {
                int d = dq * 128 + nt * 16 + lm;
                b2s[nt] = (s == 0) ? b2[e * DIM + d] : 0.f;
            }
            #pragma unroll
            for (int r = 0; r < 4; r++) {
                int tr = wid * 16 + lq * 4 + r;
                if (tr < tiln) {
                    int tok2 = btoke[t0 + tr];
                    float w = bwe[t0 + tr];
                    float* dst = accb + (size_t)tok2 * DIM;
                    #pragma unroll
                    for (int nt = 0; nt < 8; nt++) {
                        int d = dq * 128 + nt * 16 + lm;
                        atomicAdd(dst + d, w * (yacc0[nt][r] + b2s[nt]));
                    }
                }
                if (two) {
                    int tr1 = 64 + tr;
                    if (tr1 < tiln) {
                        int tok2 = btoke[t0 + tr1];
                        float w = bwe[t0 + tr1];
                        float* dst = accb + (size_t)tok2 * DIM;
                        #pragma unroll
                        for (int nt = 0; nt < 8; nt++) {
                            int d = dq * 128 + nt * 16 + lm;
                            atomicAdd(dst + d, w * (yacc1[nt][r] + b2s[nt]));
                        }
                    }
                }
            }
        }
        __syncthreads();   // protect Hs/Ws before (rare) next pass
    }
}

// ---------------- residual + LayerNorm ----------------
__global__ void ln_kernel(const float* __restrict__ x,
                          const float* __restrict__ accb,
                          const float* __restrict__ gamma,
                          const float* __restrict__ beta,
                          float* __restrict__ out) {
    const int t = blockIdx.x;
    const int tid = threadIdx.x;                  // 256
    __shared__ float red[8];
    const size_t base = (size_t)t * DIM;
    float v0 = x[base + tid] + accb[base + tid];
    float v1 = x[base + 256 + tid] + accb[base + 256 + tid];
    float s  = v0 + v1;
    float sq = v0 * v0 + v1 * v1;
    #pragma unroll
    for (int off = 32; off; off >>= 1) { s += __shfl_xor(s, off); sq += __shfl_xor(sq, off); }
    if ((tid & 63) == 0) { red[tid >> 6] = s; red[4 + (tid >> 6)] = sq; }
    __syncthreads();
    float S  = red[0] + red[1] + red[2] + red[3];
    float SQ = red[4] + red[5] + red[6] + red[7];
    float mu  = S * (1.f / DIM);
    float var = SQ * (1.f / DIM) - mu * mu;
    float inv = rsqrtf(var + LN_EPS);
    out[base + tid]       = (v0 - mu) * inv * gamma[tid]       + beta[tid];
    out[base + 256 + tid] = (v1 - mu) * inv * gamma[256 + tid] + beta[256 + tid];
}

extern "C" void kernel_launch(void* const* d_in, const int* in_sizes, int n_in,
                              void* d_out, int out_size, void* d_ws, size_t ws_size,
                              hipStream_t stream) {
    const float* x     = (const float*)d_in[0];
    const float* Wg    = (const float*)d_in[1];
    const float* bg    = (const float*)d_in[2];
    const float* W1    = (const float*)d_in[3];
    const float* b1    = (const float*)d_in[4];
    const float* W2    = (const float*)d_in[5];
    const float* b2    = (const float*)d_in[6];
    const float* gamma = (const float*)d_in[7];
    const float* beta  = (const float*)d_in[8];

    char* ws = (char*)d_ws;
    int*   counts = (int*)ws;                                  // 256 B
    int*   btok   = (int*)(ws + 4096);                          // 512 KB
    float* bwv    = (float*)(ws + 4096 + 524288);               // 512 KB
    float* accb   = (float*)(ws + 4096 + 2 * 524288);           // 4 MB

    init_kernel<<<1, NEXP, 0, stream>>>(counts);
    gate_kernel<<<NTOK, 64, 0, stream>>>(x, Wg, bg, counts, btok, bwv,
                                         (float4*)accb);
    ffn_kernel<<<NEXP * NSLICE, 256, 0, stream>>>(x, W1, b1, W2, b2,
                                                  counts, btok, bwv, accb);
    ln_kernel<<<NTOK, 256, 0, stream>>>(x, accb, gamma, beta, (float*)d_out);
}

// Round 7
// 657.245 us; speedup vs baseline: 1.1615x; 1.0146x over previous
//
#include <hip/hip_runtime.h>
#include <hip/hip_bf16.h>

#define NTOK 2048
#define DIM 512
#define HID 2048
#define NEXP 64
#define NSLICE 16
#define HSLICE 128   // HID / NSLICE
#define TTM 128      // token capacity per weight pass (binomial max ~100 < 128)
#define LN_EPS 1e-5f

// LDS layout (bytes), 42 KB/block -> 3 blocks/CU (launch_bounds(256,3)).
// EXACT round-4 structure (229 us, VGPR 84, no spills). Single change this
// round: block index remap so all 16 s-slices of expert e land on one XCD
// (bid = s*64 + e -> XCD = bid%8 = e%8). The 16 partial atomic-adds per accb
// line then cluster in ONE L2 (per-XCD footprint ~1.6MB < 4MB) instead of
// bouncing 16x through L3/HBM (r4: WRITE_SIZE 140MB ~= 17 evictions x 8MB).
//   [0, 10240)       Ws : 128 cols x 80 B (32 k bf16 + 16B pad, kg-xor swizzled)
//   [10240, 43008)   Hs : 128 tok x 128 h bf16, row 256 B, xor-swizzled chunks
#define WS_OFF 0
#define HS_OFF 10240
#define SMEM_BYTES 43008

typedef __bf16 bf16x8 __attribute__((ext_vector_type(8)));
typedef __bf16 bf16x4 __attribute__((ext_vector_type(4)));
typedef float f32x4 __attribute__((ext_vector_type(4)));

// ---------------- init: zero expert counts (accb zeroing fused into gate) ---
__global__ void init_kernel(int* __restrict__ counts) {
    counts[threadIdx.x] = 0;
}

// ---------------- gating: softmax + top2 + bucket (+ zero accb row) --------
__global__ void gate_kernel(const float* __restrict__ x,
                            const float* __restrict__ Wg,
                            const float* __restrict__ bg,
                            int* __restrict__ counts,
                            int* __restrict__ btok,
                            float* __restrict__ bw,
                            float4* __restrict__ accb4) {
    const int t = blockIdx.x;
    const int lane = threadIdx.x;  // 64 threads = 1 wave
    // zero this token's accumulator row (was init_kernel's job)
    const float4 z = make_float4(0.f, 0.f, 0.f, 0.f);
    accb4[(size_t)t * (DIM / 4) + lane] = z;
    accb4[(size_t)t * (DIM / 4) + lane + 64] = z;

    __shared__ float xs[DIM];
    const float4* xrow = (const float4*)(x + (size_t)t * DIM);
    ((float4*)xs)[lane] = xrow[lane];
    ((float4*)xs)[lane + 64] = xrow[lane + 64];
    __syncthreads();

    float acc = bg[lane];
    #pragma unroll 8
    for (int d = 0; d < DIM; d++) acc += xs[d] * Wg[d * NEXP + lane];

    float m = acc;
    #pragma unroll
    for (int off = 32; off; off >>= 1) m = fmaxf(m, __shfl_xor(m, off));
    float p = __expf(acc - m);
    float ssum = p;
    #pragma unroll
    for (int off = 32; off; off >>= 1) ssum += __shfl_xor(ssum, off);
    float prob = p / ssum;

    float v1 = prob; int i1 = lane;
    #pragma unroll
    for (int off = 32; off; off >>= 1) {
        float ov = __shfl_xor(v1, off);
        int   oi = __shfl_xor(i1, off);
        if (ov > v1 || (ov == v1 && oi < i1)) { v1 = ov; i1 = oi; }
    }
    float v2 = (lane == i1) ? -1e30f : prob; int i2 = lane;
    #pragma unroll
    for (int off = 32; off; off >>= 1) {
        float ov = __shfl_xor(v2, off);
        int   oi = __shfl_xor(i2, off);
        if (ov > v2 || (ov == v2 && oi < i2)) { v2 = ov; i2 = oi; }
    }

    if (lane == 0) {
        int s0 = atomicAdd(&counts[i1], 1);
        btok[i1 * NTOK + s0] = t;  bw[i1 * NTOK + s0] = v1;
        int s1 = atomicAdd(&counts[i2], 1);
        btok[i2 * NTOK + s1] = t;  bw[i2 * NTOK + s1] = v2;
    }
}

// Ws element offset (bf16 units) for (col 0..127, kgroup 0..3 of 8 k-values).
__device__ __forceinline__ int ws_off(int col, int kg) {
    return col * 40 + ((kg ^ ((col >> 3) & 3)) << 3);
}

// ---------------- grouped FFN: per (expert, H-slice) block ----------------
__global__ __launch_bounds__(256, 3) void ffn_kernel(
    const float* __restrict__ x,
    const float* __restrict__ W1, const float* __restrict__ b1,
    const float* __restrict__ W2, const float* __restrict__ b2,
    const int* __restrict__ counts,
    const int* __restrict__ btok, const float* __restrict__ bw,
    float* __restrict__ accb)
{
    __shared__ char smem[SMEM_BYTES];
    __bf16* wsb = (__bf16*)(smem + WS_OFF);

    // XCD-clustering remap: bid = s*64 + e  =>  e = bid&63, s = bid>>6.
    // XCD(bid) = bid % 8 = e % 8: all 16 s-slices of an expert co-locate on
    // one XCD; their atomic partial-sums to the same accb lines stay in that
    // XCD's L2. Pure index permutation: correctness-neutral (G16-safe).
    const int e = blockIdx.x & 63;
    const int s = blockIdx.x >> 6;
    const int n = counts[e];
    if (n <= 0) return;

    const int tid  = threadIdx.x;
    const int lane = tid & 63;
    const int wid  = tid >> 6;
    const int lq   = lane >> 4;                   // quad 0..3
    const int lm   = lane & 15;
    const int c0   = (tid & 31) * 4;              // staging: 4 cols
    const int r0   = (tid >> 5) * 4;              // staging: 4 k-rows

    const float* W1s = W1 + (size_t)e * DIM * HID + s * HSLICE;           // row stride HID
    const float* W2s = W2 + ((size_t)e * HID + (size_t)s * HSLICE) * DIM; // row stride DIM
    const int*   btoke = btok + e * NTOK;
    const float* bwe   = bw   + e * NTOK;

    for (int t0 = 0; t0 < n; t0 += TTM) {         // one iteration in practice
        const int tiln = min(TTM, n - t0);
        const bool two = (tiln > 64);             // block-uniform

        // wave 'wid' owns tokens g*64 + wid*16 + lm for groups g=0,1.
        const int tra0 = wid * 16 + lm;
        const int tok0 = btoke[t0 + (tra0 < tiln ? tra0 : 0)];
        const int tra1 = 64 + tra0;
        const int tok1 = two ? btoke[t0 + (tra1 < tiln ? tra1 : 0)] : tok0;
        const float* xrow0 = x + (size_t)tok0 * DIM;
        const float* xrow1 = x + (size_t)tok1 * DIM;

        // ---- Phase A: h[tiln x 128] = relu(X @ W1slice + b1) ----
        f32x4 acc0[8], acc1[8];
        #pragma unroll
        for (int i = 0; i < 8; i++) { acc0[i] = (f32x4)0.0f; acc1[i] = (f32x4)0.0f; }

        for (int ks = 0; ks < 16; ks++) {          // K = 512, 32 per step
            // issue staging + A loads to registers BEFORE the barrier
            float4 wv[4];
            const float* wp = W1s + (size_t)(ks * 32 + r0) * HID + c0;
            #pragma unroll
            for (int u = 0; u < 4; u++) wv[u] = *(const float4*)(wp + (size_t)u * HID);
            float4 a00 = *(const float4*)(xrow0 + ks * 32 + lq * 8);
            float4 a01 = *(const float4*)(xrow0 + ks * 32 + lq * 8 + 4);
            float4 a10, a11;
            if (two) {
                a10 = *(const float4*)(xrow1 + ks * 32 + lq * 8);
                a11 = *(const float4*)(xrow1 + ks * 32 + lq * 8 + 4);
            }

            __syncthreads();                        // prev readers of Ws done
            #pragma unroll
            for (int j = 0; j < 4; j++) {
                const float* f0 = (const float*)&wv[0];
                const float* f1 = (const float*)&wv[1];
                const float* f2 = (const float*)&wv[2];
                const float* f3 = (const float*)&wv[3];
                bf16x4 pk;
                pk[0] = (__bf16)f0[j]; pk[1] = (__bf16)f1[j];
                pk[2] = (__bf16)f2[j]; pk[3] = (__bf16)f3[j];
                *(bf16x4*)(wsb + ws_off(c0 + j, r0 >> 3) + (r0 & 7)) = pk;
            }
            bf16x8 af0, af1;
            {
                const float* f0 = (const float*)&a00;
                const float* f1 = (const float*)&a01;
                #pragma unroll
                for (int j = 0; j < 4; j++) { af0[j] = (__bf16)f0[j]; af0[4 + j] = (__bf16)f1[j]; }
            }
            if (two) {
                const float* f0 = (const float*)&a10;
                const float* f1 = (const float*)&a11;
                #pragma unroll
                for (int j = 0; j < 4; j++) { af1[j] = (__bf16)f0[j]; af1[4 + j] = (__bf16)f1[j]; }
            }
            __syncthreads();                        // Ws tile ready

            #pragma unroll
            for (int nt = 0; nt < 8; nt++) {
                bf16x8 bfv = *(const bf16x8*)(wsb + ws_off(nt * 16 + lm, lq));
                acc0[nt] = __builtin_amdgcn_mfma_f32_16x16x32_bf16(af0, bfv, acc0[nt], 0, 0, 0);
                if (two)
                    acc1[nt] = __builtin_amdgcn_mfma_f32_16x16x32_bf16(af1, bfv, acc1[nt], 0, 0, 0);
            }
        }

        // relu + b1 -> Hs rows of THIS wave only (no cross-wave dependency)
        #pragma unroll
        for (int nt = 0; nt < 8; nt++) {
            int hloc = nt * 16 + lm;
            float b1v = b1[e * HID + s * HSLICE + hloc];
            #pragma unroll
            for (int r = 0; r < 4; r++) {
                int tr = wid * 16 + lq * 4 + r;
                float v = fmaxf(acc0[nt][r] + b1v, 0.f);
                *(__bf16*)(smem + HS_OFF + tr * 256 +
                           (((hloc >> 3) ^ (tr & 7)) * 16) + (hloc & 7) * 2) = (__bf16)v;
                if (two) {
                    int tr1 = 64 + tr;
                    float v1 = fmaxf(acc1[nt][r] + b1v, 0.f);
                    *(__bf16*)(smem + HS_OFF + tr1 * 256 +
                               (((hloc >> 3) ^ (tr1 & 7)) * 16) + (hloc & 7) * 2) = (__bf16)v1;
                }
            }
        }
        // no barrier needed: each wave reads back only its own Hs rows.

        // ---- Phase B: Y[tiln x 512] = Hs @ W2slice ----
        for (int dq = 0; dq < 4; dq++) {            // D = 512 in 4 quarters of 128
            f32x4 yacc0[8], yacc1[8];
            #pragma unroll
            for (int i = 0; i < 8; i++) { yacc0[i] = (f32x4)0.0f; yacc1[i] = (f32x4)0.0f; }

            for (int ks = 0; ks < 4; ks++) {        // K = 128 h in 4 steps of 32
                float4 wv[4];
                const float* wp = W2s + (size_t)(ks * 32 + r0) * DIM + dq * 128 + c0;
                #pragma unroll
                for (int u = 0; u < 4; u++) wv[u] = *(const float4*)(wp + (size_t)u * DIM);

                const int trb0 = wid * 16 + lm;
                bf16x8 af0 = *(const bf16x8*)(smem + HS_OFF + trb0 * 256 +
                                              (((ks * 4 + lq) ^ (trb0 & 7)) * 16));
                bf16x8 af1;
                if (two) {
                    const int trb1 = 64 + trb0;
                    af1 = *(const bf16x8*)(smem + HS_OFF + trb1 * 256 +
                                           (((ks * 4 + lq) ^ (trb1 & 7)) * 16));
                }

                __syncthreads();                    // prev readers of Ws done
                #pragma unroll
                for (int j = 0; j < 4; j++) {
                    const float* f0 = (const float*)&wv[0];
                    const float* f1 = (const float*)&wv[1];
                    const float* f2 = (const float*)&wv[2];
                    const float* f3 = (const float*)&wv[3];
                    bf16x4 pk;
                    pk[0] = (__bf16)f0[j]; pk[1] = (__bf16)f1[j];
                    pk[2] = (__bf16)f2[j]; pk[3] = (__bf16)f3[j];
                    *(bf16x4*)(wsb + ws_off(c0 + j, r0 >> 3) + (r0 & 7)) = pk;
                }
                __syncthreads();                    // Ws tile ready

                #pragma unroll
                for (int nt = 0; nt < 8; nt++) {
                    bf16x8 bfv = *(const bf16x8*)(wsb + ws_off(nt * 16 + lm, lq));
                    yacc0[nt] = __builtin_amdgcn_mfma_f32_16x16x32_bf16(af0, bfv, yacc0[nt], 0, 0, 0);
                    if (two)
                        yacc1[nt] = __builtin_amdgcn_mfma_f32_16x16x32_bf16(af1, bfv, yacc1[nt], 0, 0, 0);
                }
            }

            // epilogue for this d-quarter: weighted atomic combine
            float b2s[8];
            #pragma unroll
            for (int nt = 0; nt < 8; nt++) {
                int d = dq * 128 + nt * 16 + lm;
                b2s[nt] = (s == 0) ? b2[e * DIM + d] : 0.f;
            }
            #pragma unroll
            for (int r = 0; r < 4; r++) {
                int tr = wid * 16 + lq * 4 + r;
                if (tr < tiln) {
                    int tok2 = btoke[t0 + tr];
                    float w = bwe[t0 + tr];
                    float* dst = accb + (size_t)tok2 * DIM;
                    #pragma unroll
                    for (int nt = 0; nt < 8; nt++) {
                        int d = dq * 128 + nt * 16 + lm;
                        atomicAdd(dst + d, w * (yacc0[nt][r] + b2s[nt]));
                    }
                }
                if (two) {
                    int tr1 = 64 + tr;
                    if (tr1 < tiln) {
                        int tok2 = btoke[t0 + tr1];
                        float w = bwe[t0 + tr1];
                        float* dst = accb + (size_t)tok2 * DIM;
                        #pragma unroll
                        for (int nt = 0; nt < 8; nt++) {
                            int d = dq * 128 + nt * 16 + lm;
                            atomicAdd(dst + d, w * (yacc1[nt][r] + b2s[nt]));
                        }
                    }
                }
            }
        }
        __syncthreads();   // protect Hs/Ws before (rare) next pass
    }
}

// ---------------- residual + LayerNorm ----------------
__global__ void ln_kernel(const float* __restrict__ x,
                          const float* __restrict__ accb,
                          const float* __restrict__ gamma,
                          const float* __restrict__ beta,
                          float* __restrict__ out) {
    const int t = blockIdx.x;
    const int tid = threadIdx.x;                  // 256
    __shared__ float red[8];
    const size_t base = (size_t)t * DIM;
    float v0 = x[base + tid] + accb[base + tid];
    float v1 = x[base + 256 + tid] + accb[base + 256 + tid];
    float s  = v0 + v1;
    float sq = v0 * v0 + v1 * v1;
    #pragma unroll
    for (int off = 32; off; off >>= 1) { s += __shfl_xor(s, off); sq += __shfl_xor(sq, off); }
    if ((tid & 63) == 0) { red[tid >> 6] = s; red[4 + (tid >> 6)] = sq; }
    __syncthreads();
    float S  = red[0] + red[1] + red[2] + red[3];
    float SQ = red[4] + red[5] + red[6] + red[7];
    float mu  = S * (1.f / DIM);
    float var = SQ * (1.f / DIM) - mu * mu;
    float inv = rsqrtf(var + LN_EPS);
    out[base + tid]       = (v0 - mu) * inv * gamma[tid]       + beta[tid];
    out[base + 256 + tid] = (v1 - mu) * inv * gamma[256 + tid] + beta[256 + tid];
}

extern "C" void kernel_launch(void* const* d_in, const int* in_sizes, int n_in,
                              void* d_out, int out_size, void* d_ws, size_t ws_size,
                              hipStream_t stream) {
    const float* x     = (const float*)d_in[0];
    const float* Wg    = (const float*)d_in[1];
    const float* bg    = (const float*)d_in[2];
    const float* W1    = (const float*)d_in[3];
    const float* b1    = (const float*)d_in[4];
    const float* W2    = (const float*)d_in[5];
    const float* b2    = (const float*)d_in[6];
    const float* gamma = (const float*)d_in[7];
    const float* beta  = (const float*)d_in[8];

    char* ws = (char*)d_ws;
    int*   counts = (int*)ws;                                  // 256 B
    int*   btok   = (int*)(ws + 4096);                          // 512 KB
    float* bwv    = (float*)(ws + 4096 + 524288);               // 512 KB
    float* accb   = (float*)(ws + 4096 + 2 * 524288);           // 4 MB

    init_kernel<<<1, NEXP, 0, stream>>>(counts);
    gate_kernel<<<NTOK, 64, 0, stream>>>(x, Wg, bg, counts, btok, bwv,
                                         (float4*)accb);
    ffn_kernel<<<NEXP * NSLICE, 256, 0, stream>>>(x, W1, b1, W2, b2,
                                                  counts, btok, bwv, accb);
    ln_kernel<<<NTOK, 256, 0, stream>>>(x, accb, gamma, beta, (float*)d_out);
}